// Round 7
// baseline (468.971 us; speedup 1.0000x reference)
//
#include <hip/hip_runtime.h>
#include <hip/hip_bf16.h>
#include <math.h>

#define SEQ   2048
#define BATCH 32
#define DIM   1024
#define MROWS (SEQ*BATCH)   // 65536 rows, r = s*32 + b
#define NT2   4             // 1024 / 256 N-tiles
#define NCH   16            // context s-chunks
#define NKT   16            // K-tiles of 64

typedef __attribute__((ext_vector_type(8))) short short8;
typedef __attribute__((ext_vector_type(8))) unsigned short u16x8;
typedef __attribute__((ext_vector_type(4))) float f32x4;

__device__ __forceinline__ unsigned short f2bf(float f) {
  unsigned u = __builtin_bit_cast(unsigned, f);
  u += 0x7FFFu + ((u >> 16) & 1u);      // round-to-nearest-even
  return (unsigned short)(u >> 16);
}

// async global -> LDS, 16 B per lane (dest = wave-uniform base + lane*16)
__device__ __forceinline__ void gl16(const unsigned short* g, unsigned short* l) {
  __builtin_amdgcn_global_load_lds(
      (const __attribute__((address_space(1))) unsigned int*)g,
      (__attribute__((address_space(3))) unsigned int*)l, 16, 0, 0);
}

// ---------------- fp32 -> bf16 bulk convert (W_enc only, 2 MB) ----------------
__global__ __launch_bounds__(256) void conv_bf16_k(const float* __restrict__ src,
                                                   unsigned short* __restrict__ dst) {
  size_t i = ((size_t)blockIdx.x * 256 + threadIdx.x) * 8;
  f32x4 a = *reinterpret_cast<const f32x4*>(src + i);
  f32x4 b = *reinterpret_cast<const f32x4*>(src + i + 4);
  u16x8 o;
  o[0] = f2bf(a[0]); o[1] = f2bf(a[1]); o[2] = f2bf(a[2]); o[3] = f2bf(a[3]);
  o[4] = f2bf(b[0]); o[5] = f2bf(b[1]); o[6] = f2bf(b[2]); o[7] = f2bf(b[3]);
  *reinterpret_cast<u16x8*>(dst + i) = o;
}

// ---------------- q[b,e] = sum_d dh[b,d] * W_dec[e,d] ----------------
__global__ __launch_bounds__(256) void qpart_k(const float* __restrict__ dh,
                                               const float* __restrict__ Wd,
                                               float* __restrict__ qpart) {
  const int bx = blockIdx.x;        // 32 blocks
  const int eb = bx & 3;            // 4 e-blocks of 256
  const int dc = bx >> 2;           // 8 d-chunks of 128
  __shared__ float ldh[BATCH][128];
  const int tid = threadIdx.x;
#pragma unroll
  for (int i = 0; i < 4; ++i) {
    int idx = tid + i * 256;
    int bb = idx >> 5, d4 = idx & 31;
    float4 v = *reinterpret_cast<const float4*>(&dh[(size_t)bb * DIM + dc * 128 + d4 * 4]);
    *reinterpret_cast<float4*>(&ldh[bb][d4 * 4]) = v;
  }
  __syncthreads();
  const int e = eb * 256 + tid;
  float acc[BATCH];
#pragma unroll
  for (int b = 0; b < BATCH; ++b) acc[b] = 0.f;
  for (int d4 = 0; d4 < 32; ++d4) {
    float4 w = *reinterpret_cast<const float4*>(&Wd[(size_t)e * DIM + dc * 128 + d4 * 4]);
#pragma unroll
    for (int b = 0; b < BATCH; ++b) {
      float4 h = *reinterpret_cast<const float4*>(&ldh[b][d4 * 4]);
      acc[b] += w.x * h.x + w.y * h.y + w.z * h.z + w.w * h.w;
    }
  }
#pragma unroll
  for (int b = 0; b < BATCH; ++b)
    qpart[((size_t)dc * BATCH + b) * DIM + e] = acc[b];
}

__global__ __launch_bounds__(256) void qred_k(const float* __restrict__ qpart,
                                              float* __restrict__ q) {
  int i = blockIdx.x * 256 + threadIdx.x;
  float s = 0.f;
#pragma unroll
  for (int dc = 0; dc < 8; ++dc) s += qpart[(size_t)dc * 32768 + i];
  q[i] = s;
}

// ============ 256^2 8-phase fused GEMM, fp32-A fused conversion ============
// A-staging: reg-stage fp32 enc -> f2bf -> ds_write, SAME LDS image as R6's gl16.
// B-staging: gl16 unchanged. vmcnt ledger: VMC(2) at each odd phase drains both
// the A-loads issued 2 phases prior AND the B-gl16 needed >=2 phases later.
// WAR: every piece overwrite >=2 barriers after its last ds_read (audited).
#define BARR  __builtin_amdgcn_s_barrier()
#define LGKM0 do { asm volatile("s_waitcnt lgkmcnt(0)" ::: "memory"); \
                   __builtin_amdgcn_sched_barrier(0); } while (0)
#define VMC(n) asm volatile("s_waitcnt vmcnt(" #n ")" ::: "memory")

// issue 4 f32x4 loads for A piece (t,h) into reg set P (two LDS slots' worth)
#define ALOADS(P, t, h) do {                                                      \
    const float* pa_ = Af + (size_t)(gA0 + (h) * 64) * 1024 + (t) * 64 + cSt * 8; \
    P##0 = *(const f32x4*)pa_;                                                    \
    P##1 = *(const f32x4*)(pa_ + 4);                                              \
    P##2 = *(const f32x4*)(pa_ + 131072);                                         \
    P##3 = *(const f32x4*)(pa_ + 131072 + 4);                                     \
  } while (0)

#define AWRITE_BODY(P, t, h) do {                                                 \
    u16x8 w0_, w1_;                                                               \
    w0_[0]=f2bf(P##0[0]); w0_[1]=f2bf(P##0[1]); w0_[2]=f2bf(P##0[2]);             \
    w0_[3]=f2bf(P##0[3]); w0_[4]=f2bf(P##1[0]); w0_[5]=f2bf(P##1[1]);             \
    w0_[6]=f2bf(P##1[2]); w0_[7]=f2bf(P##1[3]);                                   \
    w1_[0]=f2bf(P##2[0]); w1_[1]=f2bf(P##2[1]); w1_[2]=f2bf(P##2[2]);             \
    w1_[3]=f2bf(P##2[3]); w1_[4]=f2bf(P##3[0]); w1_[5]=f2bf(P##3[1]);             \
    w1_[6]=f2bf(P##3[2]); w1_[7]=f2bf(P##3[3]);                                   \
    char* lb_ = arena + (((t) & 1) * 65536) + (h) * 16384;                        \
    *(u16x8*)(lb_ + tid * 16) = w0_;                                              \
    *(u16x8*)(lb_ + 8192 + tid * 16) = w1_;                                       \
  } while (0)

#define AWRITE(P, t, h)  do { VMC(2); AWRITE_BODY(P, t, h); } while (0)
#define AWRITE0(P, t, h) do { VMC(0); AWRITE_BODY(P, t, h); } while (0)

#define STAGE_B(t, h) do {                                                        \
    const unsigned short* gb_ = Bbase + (size_t)(t) * 64;                         \
    char* lb_ = arena + (((t) & 1) * 65536) + 32768 + (h) * 16384;                \
    gl16(gb_ + (size_t)(gB0 + (h) * 32) * 1024 + cSt * 8,                         \
         (unsigned short*)lb_ + w * 512);                                         \
    gl16(gb_ + (size_t)(gB0 + 128 + (h) * 32) * 1024 + cSt * 8,                   \
         (unsigned short*)(lb_ + 8192) + w * 512);                                \
  } while (0)

#define LOAD_A(d, MH) do {                                                        \
    const char* bA_ = arena + (d) * 65536 + (MH) * 16384;                         \
    _Pragma("unroll") for (int i_ = 0; i_ < 4; ++i_)                              \
    _Pragma("unroll") for (int ks_ = 0; ks_ < 2; ++ks_) {                         \
      int lrow_ = wr * 64 + i_ * 16 + fr;                                         \
      int lc_ = (ks_ * 4 + kq) ^ (fr & 7);                                        \
      a[i_][ks_] = *(const short8*)(bA_ + lrow_ * 128 + lc_ * 16);                \
    } } while (0)

#define LOAD_B(d, NH) do {                                                        \
    const char* bB_ = arena + (d) * 65536 + 32768 + (NH) * 16384;                 \
    _Pragma("unroll") for (int j_ = 0; j_ < 2; ++j_)                              \
    _Pragma("unroll") for (int ks_ = 0; ks_ < 2; ++ks_) {                         \
      int lrow_ = wc * 32 + j_ * 16 + fr;                                         \
      int lc_ = (ks_ * 4 + kq) ^ (fr & 7);                                        \
      b[NH][j_][ks_] = *(const short8*)(bB_ + lrow_ * 128 + lc_ * 16);            \
    } } while (0)

#define DO_QUAD(MH, NH) do {                                                      \
    __builtin_amdgcn_s_setprio(1);                                                \
    _Pragma("unroll") for (int i_ = 0; i_ < 4; ++i_)                              \
    _Pragma("unroll") for (int j_ = 0; j_ < 2; ++j_)                              \
    _Pragma("unroll") for (int ks_ = 0; ks_ < 2; ++ks_)                           \
      acc[(MH) * 4 + i_][(NH) * 2 + j_] =                                         \
          __builtin_amdgcn_mfma_f32_16x16x32_bf16(                                \
              a[i_][ks_], b[NH][j_][ks_], acc[(MH) * 4 + i_][(NH) * 2 + j_],      \
              0, 0, 0);                                                           \
    __builtin_amdgcn_s_setprio(0);                                                \
  } while (0)

__global__ __launch_bounds__(512, 2) void gemm8p(const float* __restrict__ Aenc,
                                                 const unsigned short* __restrict__ B,
                                                 const float* __restrict__ q,
                                                 const float* __restrict__ V,
                                                 float* __restrict__ lpart) {
  __shared__ __align__(16) char arena[131072];   // 2 bufs x (A 32KB | B 32KB)

  const int bid = blockIdx.x;
  const int wg = (bid & 7) * 128 + (bid >> 3);   // XCD-bijective (1024 % 8 == 0)
  const int mt = wg >> 2, nt = wg & 3;
  const int row0 = mt * 256, col0 = nt * 256;
  const int tid = threadIdx.x;
  const int lane = tid & 63, w = tid >> 6;
  const int wr = w >> 2, wc = w & 3;             // 2 x 4 waves, each 128x64 out
  const int fr = lane & 15, kq = lane >> 4;

  // stage lane geometry: slot u -> piece lrow = u>>3, chunk (u&7)^(lrow&7)
  const int lr0 = tid >> 3;                      // 0..63
  const int cSt = (tid & 7) ^ (lr0 & 7);
  const int gA0 = lr0;                           // A piece h: rows gA0+h*64, +128
  const int gB0 = (lr0 & 31) + (lr0 >> 5) * 64;  // B piece h: rows gB0+h*32, +128

  const float* Af = Aenc + (size_t)row0 * DIM;
  const unsigned short* Bbase = B + (size_t)col0 * DIM;

  f32x4 acc[8][4];
#pragma unroll
  for (int i = 0; i < 8; ++i)
#pragma unroll
    for (int j = 0; j < 4; ++j) acc[i][j] = (f32x4)(0.f);

  short8 a[4][2];        // current A-half fragments
  short8 b[2][2][2];     // both B halves: NH x j x ks
  f32x4 X0, X1, X2, X3, Y0, Y1, Y2, Y3;   // A staging windows

  // ---- prologue ----
  ALOADS(X, 0, 0); AWRITE0(X, 0, 0);
  ALOADS(X, 0, 1); AWRITE0(X, 0, 1);
  ALOADS(X, 1, 0); AWRITE0(X, 1, 0);
  STAGE_B(0, 0); STAGE_B(0, 1);        // t0.B (4 vmem)
  ALOADS(X, 1, 1);                     // t1.Ah1 -> X (4 vmem), written at p1
  STAGE_B(1, 0);                       // t1.Bh0 (2 vmem, trailing pair)
  VMC(6);                              // drain t0.B; leaves [X(4), t1.Bh0(2)]
  LGKM0;
  BARR;

#pragma unroll 1
  for (int t2 = 0; t2 < NKT; t2 += 2) {
    const bool last = (t2 == NKT - 2);
    // p1: quad(M0,N0) of tile t2 (buf0); write (t2+1).Ah1; load (t2+2).Ah0
    LOAD_A(0, 0); LOAD_B(0, 0);
    AWRITE(X, t2 + 1, 1);
    if (!last) ALOADS(Y, t2 + 2, 0);
    BARR; LGKM0; DO_QUAD(0, 0); BARR;
    // p2: (M0,N1); stage (t2+1).Bh1
    LOAD_B(0, 1);
    STAGE_B(t2 + 1, 1);
    BARR; LGKM0; DO_QUAD(0, 1); BARR;
    // p3: (M1,N0); write (t2+2).Ah0; load (t2+2).Ah1
    LOAD_A(0, 1);
    if (!last) { AWRITE(Y, t2 + 2, 0); ALOADS(X, t2 + 2, 1); } else { VMC(0); }
    BARR; LGKM0; DO_QUAD(1, 0); BARR;
    // p4: (M1,N1); stage (t2+2).Bh0
    if (!last) STAGE_B(t2 + 2, 0);
    BARR; LGKM0; DO_QUAD(1, 1); BARR;
    // p5: quad(M0,N0) of tile t2+1 (buf1); write (t2+2).Ah1; load (t2+3).Ah0
    LOAD_A(1, 0); LOAD_B(1, 0);
    if (!last) { AWRITE(X, t2 + 2, 1); ALOADS(Y, t2 + 3, 0); } else { VMC(0); }
    BARR; LGKM0; DO_QUAD(0, 0); BARR;
    // p6: (M0,N1); stage (t2+2).Bh1
    LOAD_B(1, 1);
    if (!last) STAGE_B(t2 + 2, 1);
    BARR; LGKM0; DO_QUAD(0, 1); BARR;
    // p7: (M1,N0); write (t2+3).Ah0; load (t2+3).Ah1
    LOAD_A(1, 1);
    if (!last) { AWRITE(Y, t2 + 3, 0); ALOADS(X, t2 + 3, 1); } else { VMC(0); }
    BARR; LGKM0; DO_QUAD(1, 0); BARR;
    // p8: (M1,N1); stage (t2+3).Bh0
    if (!last) STAGE_B(t2 + 3, 0);
    BARR; LGKM0; DO_QUAD(1, 1); BARR;
  }

  // ================= epilogue =================
  __syncthreads();                 // staging LDS dead; overlay q/V/red
  float* qld = (float*)arena;                    // [32][260] padded
  float* vld = (float*)(arena + 33280);          // [256]
  float* red = (float*)(arena + 34304);          // [4][256]
#pragma unroll
  for (int i = 0; i < 4; ++i) {
    int id = i * 512 + tid;                      // 2048 float4s
    int bb = id >> 6, e4 = id & 63;
    float4 v = *(const float4*)&q[(size_t)bb * DIM + col0 + e4 * 4];
    *(float4*)&qld[bb * 260 + e4 * 4] = v;
  }
  if (tid < 64) *(float4*)&vld[tid * 4] = *(const float4*)&V[col0 + tid * 4];
  __syncthreads();

#pragma unroll
  for (int mf = 0; mf < 8; ++mf) {
#pragma unroll
    for (int reg = 0; reg < 4; ++reg) {
      const int m_loc = wr * 128 + mf * 16 + kq * 4 + reg;
      const int bb = m_loc & 31;                 // row0 % 32 == 0
      float val = 0.f;
#pragma unroll
      for (int nf = 0; nf < 4; ++nf) {
        const int el = wc * 64 + nf * 16 + fr;
        float x = acc[mf][nf][reg] + qld[bb * 260 + el];
        float g = __expf(2.f * x);
        float tnh = 1.f - 2.f * __builtin_amdgcn_rcpf(g + 1.f);
        val += tnh * vld[el];
      }
      val += __shfl_xor(val, 1); val += __shfl_xor(val, 2);
      val += __shfl_xor(val, 4); val += __shfl_xor(val, 8);
      if (fr == 0) red[wc * 256 + m_loc] = val;
    }
  }
  __syncthreads();
  if (tid < 256) {
    float s = red[tid] + red[256 + tid] + red[512 + tid] + red[768 + tid];
    lpart[(size_t)(row0 + tid) * NT2 + nt] = s;
  }
}

// ---------------- softmax over seq per batch ----------------
__global__ __launch_bounds__(256) void softmax_k(const float* __restrict__ lpart,
                                                 float* __restrict__ alpha) {
  const int b = blockIdx.x;
  __shared__ float lv[SEQ];
  __shared__ float sred[4];
  const int tid = threadIdx.x;
  float mx = -1e30f;
  for (int s = tid; s < SEQ; s += 256) {
    const float* p = &lpart[(size_t)(s * BATCH + b) * NT2];
    float v = p[0] + p[1] + p[2] + p[3];
    lv[s] = v;
    mx = fmaxf(mx, v);
  }
#pragma unroll
  for (int off = 32; off >= 1; off >>= 1) mx = fmaxf(mx, __shfl_xor(mx, off));
  if ((tid & 63) == 0) sred[tid >> 6] = mx;
  __syncthreads();
  mx = fmaxf(fmaxf(sred[0], sred[1]), fmaxf(sred[2], sred[3]));
  __syncthreads();
  float sm = 0.f;
  for (int s = tid; s < SEQ; s += 256) {
    float e = expf(lv[s] - mx);
    lv[s] = e;
    sm += e;
  }
#pragma unroll
  for (int off = 32; off >= 1; off >>= 1) sm += __shfl_xor(sm, off);
  if ((tid & 63) == 0) sred[tid >> 6] = sm;
  __syncthreads();
  const float inv = 1.f / (sred[0] + sred[1] + sred[2] + sred[3]);
  for (int s = tid; s < SEQ; s += 256)
    alpha[(size_t)b * SEQ + s] = lv[s] * inv;
}

// ---------------- context partials: sum_s alpha[b,s]*enc[s,b,:] (fp32) --------
__global__ __launch_bounds__(256) void ctx_part_k(const float* __restrict__ enc,
                                                  const float* __restrict__ alpha,
                                                  float* __restrict__ cpart) {
  const int blk = blockIdx.x;                  // 512 blocks
  const int b = blk & 31;
  const int ch = blk >> 5;
  const int tid = threadIdx.x;                 // float4 lane over DIM
  const int s0 = ch * (SEQ / NCH);
  float4 acc = make_float4(0.f, 0.f, 0.f, 0.f);
#pragma unroll 4
  for (int i = 0; i < SEQ / NCH; ++i) {
    const int s = s0 + i;
    const float a = alpha[(size_t)b * SEQ + s];
    float4 v = *reinterpret_cast<const float4*>(
        &enc[((size_t)s * BATCH + b) * DIM + tid * 4]);
    acc.x += a * v.x; acc.y += a * v.y; acc.z += a * v.z; acc.w += a * v.w;
  }
  *reinterpret_cast<float4*>(&cpart[((size_t)ch * BATCH + b) * DIM + tid * 4]) = acc;
}

__global__ __launch_bounds__(256) void ctxred_k(const float* __restrict__ cpart,
                                                float* __restrict__ out) {
  int i = blockIdx.x * 256 + threadIdx.x;
  float s = 0.f;
#pragma unroll
  for (int ch = 0; ch < NCH; ++ch) s += cpart[(size_t)ch * 32768 + i];
  out[i] = s;
}

extern "C" void kernel_launch(void* const* d_in, const int* in_sizes, int n_in,
                              void* d_out, int out_size, void* d_ws, size_t ws_size,
                              hipStream_t stream) {
  const float* dh   = (const float*)d_in[0];   // (32,1,1024)
  const float* enc  = (const float*)d_in[1];   // (2048,32,1024)
  const float* Wenc = (const float*)d_in[2];   // (1024,1024)
  const float* Wdec = (const float*)d_in[3];   // (1024,1024)
  const float* Vatt = (const float*)d_in[4];   // (1,1024)
  float* out = (float*)d_out;                  // [0,32768) context, [32768,98304) alpha

  float* ws = (float*)d_ws;
  float* q      = ws;                                   // 32768
  float* qpart  = ws + 32768;                           // 262144
  float* lpart  = ws + 294912;                          // 262144
  float* cpart  = ws + 557056;                          // 16*32768 = 524288
  unsigned short* Wbf = (unsigned short*)(ws + 1081344);// 1Mi bf16

  conv_bf16_k<<<dim3(512),   dim3(256), 0, stream>>>(Wenc, Wbf);
  qpart_k    <<<dim3(32),    dim3(256), 0, stream>>>(dh, Wdec, qpart);
  qred_k     <<<dim3(128),   dim3(256), 0, stream>>>(qpart, q);
  gemm8p     <<<dim3(1024),  dim3(512), 0, stream>>>(enc, Wbf, q, Vatt, lpart);
  softmax_k  <<<dim3(BATCH),     dim3(256), 0, stream>>>(lpart, out + 32768);
  ctx_part_k <<<dim3(BATCH*NCH), dim3(256), 0, stream>>>(enc, out + 32768, cpart);
  ctxred_k   <<<dim3(128),       dim3(256), 0, stream>>>(cpart, out);
}

// Round 8
// 299.674 us; speedup vs baseline: 1.5649x; 1.5649x over previous
//
#include <hip/hip_runtime.h>
#include <hip/hip_bf16.h>
#include <math.h>

#define SEQ   2048
#define BATCH 32
#define DIM   1024
#define MROWS (SEQ*BATCH)   // 65536 rows, r = s*32 + b
#define NT2   4             // 1024 / 256 N-tiles
#define NCH   16            // context s-chunks (x2 sub-chunks inside kernel)
#define NKT   16            // K-tiles of 64

typedef __attribute__((ext_vector_type(8))) short short8;
typedef __attribute__((ext_vector_type(8))) unsigned short u16x8;
typedef __attribute__((ext_vector_type(4))) float f32x4;

__device__ __forceinline__ unsigned short f2bf(float f) {
  unsigned u = __builtin_bit_cast(unsigned, f);
  u += 0x7FFFu + ((u >> 16) & 1u);      // round-to-nearest-even
  return (unsigned short)(u >> 16);
}

// async global -> LDS, 16 B per lane (dest = wave-uniform base + lane*16)
__device__ __forceinline__ void gl16(const unsigned short* g, unsigned short* l) {
  __builtin_amdgcn_global_load_lds(
      (const __attribute__((address_space(1))) unsigned int*)g,
      (__attribute__((address_space(3))) unsigned int*)l, 16, 0, 0);
}

// ---------------- fp32 -> bf16 bulk convert ----------------
__global__ __launch_bounds__(256) void conv_bf16_k(const float* __restrict__ src,
                                                   unsigned short* __restrict__ dst) {
  size_t i = ((size_t)blockIdx.x * 256 + threadIdx.x) * 8;
  f32x4 a = __builtin_nontemporal_load(reinterpret_cast<const f32x4*>(src + i));
  f32x4 b = __builtin_nontemporal_load(reinterpret_cast<const f32x4*>(src + i + 4));
  u16x8 o;
  o[0] = f2bf(a[0]); o[1] = f2bf(a[1]); o[2] = f2bf(a[2]); o[3] = f2bf(a[3]);
  o[4] = f2bf(b[0]); o[5] = f2bf(b[1]); o[6] = f2bf(b[2]); o[7] = f2bf(b[3]);
  *reinterpret_cast<u16x8*>(dst + i) = o;
}

// ---------------- q[b,e] = sum_d dh[b,d] * W_dec[e,d] ----------------
__global__ __launch_bounds__(256) void qpart_k(const float* __restrict__ dh,
                                               const float* __restrict__ Wd,
                                               float* __restrict__ qpart) {
  const int bx = blockIdx.x;        // 32 blocks
  const int eb = bx & 3;            // 4 e-blocks of 256
  const int dc = bx >> 2;           // 8 d-chunks of 128
  __shared__ float ldh[BATCH][128];
  const int tid = threadIdx.x;
#pragma unroll
  for (int i = 0; i < 4; ++i) {
    int idx = tid + i * 256;
    int bb = idx >> 5, d4 = idx & 31;
    float4 v = *reinterpret_cast<const float4*>(&dh[(size_t)bb * DIM + dc * 128 + d4 * 4]);
    *reinterpret_cast<float4*>(&ldh[bb][d4 * 4]) = v;
  }
  __syncthreads();
  const int e = eb * 256 + tid;
  float acc[BATCH];
#pragma unroll
  for (int b = 0; b < BATCH; ++b) acc[b] = 0.f;
  for (int d4 = 0; d4 < 32; ++d4) {
    float4 w = *reinterpret_cast<const float4*>(&Wd[(size_t)e * DIM + dc * 128 + d4 * 4]);
#pragma unroll
    for (int b = 0; b < BATCH; ++b) {
      float4 h = *reinterpret_cast<const float4*>(&ldh[b][d4 * 4]);
      acc[b] += w.x * h.x + w.y * h.y + w.z * h.z + w.w * h.w;
    }
  }
#pragma unroll
  for (int b = 0; b < BATCH; ++b)
    qpart[((size_t)dc * BATCH + b) * DIM + e] = acc[b];
}

__global__ __launch_bounds__(256) void qred_k(const float* __restrict__ qpart,
                                              float* __restrict__ q) {
  int i = blockIdx.x * 256 + threadIdx.x;
  float s = 0.f;
#pragma unroll
  for (int dc = 0; dc < 8; ++dc) s += qpart[(size_t)dc * 32768 + i];
  q[i] = s;
}

// ============ 256^2 8-phase fused GEMM, rebalanced ds_reads ============
// R6 structure (proven): piece-aligned LDS layout, 2 barriers/phase, LGKM0 fence,
// VMC(4) at p4/p8. NEW: per-phase pre-barrier reads capped at 8; all other
// fragment loads issue AFTER the LGKM0 fence, overlapped with the MFMA cluster
// (they feed FUTURE quads). Register sets a0/a1/b0/b1 statically named.
#define BARR  __builtin_amdgcn_s_barrier()
#define LGKM0 do { asm volatile("s_waitcnt lgkmcnt(0)" ::: "memory"); \
                   __builtin_amdgcn_sched_barrier(0); } while (0)
#define VMC(n) asm volatile("s_waitcnt vmcnt(" #n ")" ::: "memory")

#define STAGE_A(t, h) do {                                                        \
    const unsigned short* gb_ = Abase + (size_t)(t) * 64;                         \
    char* lb_ = arena + (((t) & 1) * 65536) + (h) * 16384;                        \
    gl16(gb_ + (size_t)(gA0 + (h) * 64) * 1024 + cSt * 8,                         \
         (unsigned short*)lb_ + w * 512);                                         \
    gl16(gb_ + (size_t)(gA0 + 128 + (h) * 64) * 1024 + cSt * 8,                   \
         (unsigned short*)(lb_ + 8192) + w * 512);                                \
  } while (0)

#define STAGE_B(t, h) do {                                                        \
    const unsigned short* gb_ = Bbase + (size_t)(t) * 64;                         \
    char* lb_ = arena + (((t) & 1) * 65536) + 32768 + (h) * 16384;                \
    gl16(gb_ + (size_t)(gB0 + (h) * 32) * 1024 + cSt * 8,                         \
         (unsigned short*)lb_ + w * 512);                                         \
    gl16(gb_ + (size_t)(gB0 + 128 + (h) * 32) * 1024 + cSt * 8,                   \
         (unsigned short*)(lb_ + 8192) + w * 512);                                \
  } while (0)

#define LOAD_A(SET, d, MH) do {                                                   \
    const char* bA_ = arena + (d) * 65536 + (MH) * 16384;                         \
    _Pragma("unroll") for (int i_ = 0; i_ < 4; ++i_)                              \
    _Pragma("unroll") for (int ks_ = 0; ks_ < 2; ++ks_) {                         \
      int lrow_ = wr * 64 + i_ * 16 + fr;                                         \
      int lc_ = (ks_ * 4 + kq) ^ (fr & 7);                                        \
      SET[i_][ks_] = *(const short8*)(bA_ + lrow_ * 128 + lc_ * 16);              \
    } } while (0)

#define LOAD_B(SET, d, NH) do {                                                   \
    const char* bB_ = arena + (d) * 65536 + 32768 + (NH) * 16384;                 \
    _Pragma("unroll") for (int j_ = 0; j_ < 2; ++j_)                              \
    _Pragma("unroll") for (int ks_ = 0; ks_ < 2; ++ks_) {                         \
      int lrow_ = wc * 32 + j_ * 16 + fr;                                         \
      int lc_ = (ks_ * 4 + kq) ^ (fr & 7);                                        \
      SET[j_][ks_] = *(const short8*)(bB_ + lrow_ * 128 + lc_ * 16);              \
    } } while (0)

#define DO_QUAD(ASET, BSET, MH, NH) do {                                          \
    __builtin_amdgcn_s_setprio(1);                                                \
    _Pragma("unroll") for (int i_ = 0; i_ < 4; ++i_)                              \
    _Pragma("unroll") for (int j_ = 0; j_ < 2; ++j_)                              \
    _Pragma("unroll") for (int ks_ = 0; ks_ < 2; ++ks_)                           \
      acc[(MH) * 4 + i_][(NH) * 2 + j_] =                                         \
          __builtin_amdgcn_mfma_f32_16x16x32_bf16(                                \
              ASET[i_][ks_], BSET[j_][ks_], acc[(MH) * 4 + i_][(NH) * 2 + j_],    \
              0, 0, 0);                                                           \
    __builtin_amdgcn_s_setprio(0);                                                \
  } while (0)

__global__ __launch_bounds__(512, 2) void gemm8p(const unsigned short* __restrict__ A,
                                                 const unsigned short* __restrict__ B,
                                                 const float* __restrict__ q,
                                                 const float* __restrict__ V,
                                                 float* __restrict__ lpart) {
  __shared__ __align__(16) char arena[131072];   // 2 bufs x (A 32KB | B 32KB)

  const int bid = blockIdx.x;
  const int wg = (bid & 7) * 128 + (bid >> 3);   // XCD-bijective (1024 % 8 == 0)
  const int mt = wg >> 2, nt = wg & 3;
  const int row0 = mt * 256, col0 = nt * 256;
  const int tid = threadIdx.x;
  const int lane = tid & 63, w = tid >> 6;
  const int wr = w >> 2, wc = w & 3;             // 2 x 4 waves, each 128x64 out
  const int fr = lane & 15, kq = lane >> 4;

  // stage lane geometry: slot u -> piece lrow = u>>3, chunk (u&7)^(lrow&7)
  const int lr0 = tid >> 3;                      // 0..63
  const int cSt = (tid & 7) ^ (lr0 & 7);
  const int gA0 = lr0;                           // A piece h: rows gA0+h*64, +128
  const int gB0 = (lr0 & 31) + (lr0 >> 5) * 64;  // B piece h: rows gB0+h*32, +128

  const unsigned short* Abase = A + (size_t)row0 * DIM;
  const unsigned short* Bbase = B + (size_t)col0 * DIM;

  f32x4 acc[8][4];
#pragma unroll
  for (int i = 0; i < 8; ++i)
#pragma unroll
    for (int j = 0; j < 4; ++j) acc[i][j] = (f32x4)(0.f);

  short8 a0[4][2], a1[4][2];   // M0 / M1 fragment sets
  short8 b0[2][2], b1[2][2];   // N0 / N1 fragment sets

  // ---- prologue: tile0 full + tile1 h0 pieces; drain; barrier; preload b0 ----
  STAGE_A(0, 0); STAGE_B(0, 0); STAGE_A(0, 1); STAGE_B(0, 1);
  STAGE_A(1, 0); STAGE_B(1, 0);
  VMC(0);
  BARR;
  LOAD_B(b0, 0, 0);

#pragma unroll 1
  for (int t2 = 0; t2 < NKT; t2 += 2) {
    const bool last = (t2 == NKT - 2);
    // p1: quad (M0,N0) tile t2 (buf0)
    LOAD_A(a0, 0, 0);
    STAGE_A(t2 + 1, 1);
    BARR; LGKM0;
    LOAD_B(b1, 0, 1);                 // overlapped with MFMA (feeds p2)
    DO_QUAD(a0, b0, 0, 0); BARR;
    // p2: (M0,N1)
    STAGE_B(t2 + 1, 1);
    BARR; LGKM0;
    LOAD_A(a1, 0, 1);                 // overlapped (feeds p3/p4)
    DO_QUAD(a0, b1, 0, 1); BARR;
    // p3: (M1,N0)
    if (!last) STAGE_A(t2 + 2, 0);
    BARR; LGKM0;
    DO_QUAD(a1, b0, 1, 0); BARR;
    // p4: (M1,N1) + K-tile drain
    if (!last) { STAGE_B(t2 + 2, 0); VMC(4); } else { VMC(0); }
    BARR; LGKM0;
    LOAD_B(b0, 1, 0);                 // overlapped (feeds p5/p7; drained by this VMC)
    DO_QUAD(a1, b1, 1, 1); BARR;
    // p5: quad (M0,N0) tile t2+1 (buf1)
    LOAD_A(a0, 1, 0);
    if (!last) STAGE_A(t2 + 2, 1);
    BARR; LGKM0;
    LOAD_B(b1, 1, 1);                 // overlapped (feeds p6/p8)
    DO_QUAD(a0, b0, 0, 0); BARR;
    // p6: (M0,N1)
    if (!last) STAGE_B(t2 + 2, 1);
    BARR; LGKM0;
    LOAD_A(a1, 1, 1);                 // overlapped (feeds p7/p8)
    DO_QUAD(a0, b1, 0, 1); BARR;
    // p7: (M1,N0)
    if (!last) STAGE_A(t2 + 3, 0);
    BARR; LGKM0;
    DO_QUAD(a1, b0, 1, 0); BARR;
    // p8: (M1,N1) + K-tile drain
    if (!last) { STAGE_B(t2 + 3, 0); VMC(4); }
    BARR; LGKM0;
    if (!last) LOAD_B(b0, 0, 0);      // overlapped (feeds next iter p1/p3)
    DO_QUAD(a1, b1, 1, 1); BARR;
  }

  // ================= epilogue =================
  __syncthreads();                 // staging LDS dead; overlay q/V/red
  float* qld = (float*)arena;                    // [32][260] padded
  float* vld = (float*)(arena + 33280);          // [256]
  float* red = (float*)(arena + 34304);          // [4][256]
#pragma unroll
  for (int i = 0; i < 4; ++i) {
    int id = i * 512 + tid;                      // 2048 float4s
    int bb = id >> 6, e4 = id & 63;
    float4 v = *(const float4*)&q[(size_t)bb * DIM + col0 + e4 * 4];
    *(float4*)&qld[bb * 260 + e4 * 4] = v;
  }
  if (tid < 64) *(float4*)&vld[tid * 4] = *(const float4*)&V[col0 + tid * 4];
  __syncthreads();

#pragma unroll
  for (int mf = 0; mf < 8; ++mf) {
#pragma unroll
    for (int reg = 0; reg < 4; ++reg) {
      const int m_loc = wr * 128 + mf * 16 + kq * 4 + reg;
      const int bb = m_loc & 31;                 // row0 % 32 == 0
      float val = 0.f;
#pragma unroll
      for (int nf = 0; nf < 4; ++nf) {
        const int el = wc * 64 + nf * 16 + fr;
        float x = acc[mf][nf][reg] + qld[bb * 260 + el];
        float g = __expf(2.f * x);
        float tnh = 1.f - 2.f * __builtin_amdgcn_rcpf(g + 1.f);
        val += tnh * vld[el];
      }
      val += __shfl_xor(val, 1); val += __shfl_xor(val, 2);
      val += __shfl_xor(val, 4); val += __shfl_xor(val, 8);
      if (fr == 0) red[wc * 256 + m_loc] = val;
    }
  }
  __syncthreads();
  if (tid < 256) {
    float s = red[tid] + red[256 + tid] + red[512 + tid] + red[768 + tid];
    lpart[(size_t)(row0 + tid) * NT2 + nt] = s;
  }
}

// ---------------- softmax over seq per batch ----------------
__global__ __launch_bounds__(256) void softmax_k(const float* __restrict__ lpart,
                                                 float* __restrict__ alpha) {
  const int b = blockIdx.x;
  __shared__ float lv[SEQ];
  __shared__ float sred[4];
  const int tid = threadIdx.x;
  float mx = -1e30f;
  for (int s = tid; s < SEQ; s += 256) {
    const float* p = &lpart[(size_t)(s * BATCH + b) * NT2];
    float v = p[0] + p[1] + p[2] + p[3];
    lv[s] = v;
    mx = fmaxf(mx, v);
  }
#pragma unroll
  for (int off = 32; off >= 1; off >>= 1) mx = fmaxf(mx, __shfl_xor(mx, off));
  if ((tid & 63) == 0) sred[tid >> 6] = mx;
  __syncthreads();
  mx = fmaxf(fmaxf(sred[0], sred[1]), fmaxf(sred[2], sred[3]));
  __syncthreads();
  float sm = 0.f;
  for (int s = tid; s < SEQ; s += 256) {
    float e = expf(lv[s] - mx);
    lv[s] = e;
    sm += e;
  }
#pragma unroll
  for (int off = 32; off >= 1; off >>= 1) sm += __shfl_xor(sm, off);
  if ((tid & 63) == 0) sred[tid >> 6] = sm;
  __syncthreads();
  const float inv = 1.f / (sred[0] + sred[1] + sred[2] + sred[3]);
  for (int s = tid; s < SEQ; s += 256)
    alpha[(size_t)b * SEQ + s] = lv[s] * inv;
}

// ---------------- context partials from bf16 enc copy ----------------
__global__ __launch_bounds__(256) void ctx_part_k(const unsigned short* __restrict__ encbf,
                                                  const float* __restrict__ alpha,
                                                  float* __restrict__ cpart) {
  const int blk = blockIdx.x;                   // 512 blocks
  const int b = blk & 31;
  const int ch = blk >> 5;                      // 0..15
  const int tid = threadIdx.x;
  const int g = tid >> 7;                       // 0/1 sub-chunk
  const int d0 = (tid & 127) * 8;
  const int s0 = ch * (SEQ / NCH);
  float acc8[8];
#pragma unroll
  for (int k = 0; k < 8; ++k) acc8[k] = 0.f;
#pragma unroll 4
  for (int i = 0; i < SEQ / NCH; i += 2) {
    const int s = s0 + i + g;
    const float a = alpha[(size_t)b * SEQ + s];
    u16x8 v = *reinterpret_cast<const u16x8*>(&encbf[((size_t)s * BATCH + b) * DIM + d0]);
#pragma unroll
    for (int k = 0; k < 8; ++k) {
      float f = __builtin_bit_cast(float, (unsigned)v[k] << 16);
      acc8[k] += a * f;
    }
  }
  size_t o = ((size_t)(ch * 2 + g) * BATCH + b) * DIM + d0;
  float4 lo = {acc8[0], acc8[1], acc8[2], acc8[3]};
  float4 hi = {acc8[4], acc8[5], acc8[6], acc8[7]};
  *(float4*)&cpart[o] = lo;
  *(float4*)&cpart[o + 4] = hi;
}

__global__ __launch_bounds__(256) void ctxred_k(const float* __restrict__ cpart,
                                                float* __restrict__ out) {
  int i = blockIdx.x * 256 + threadIdx.x;
  float s = 0.f;
#pragma unroll
  for (int ch = 0; ch < 32; ++ch) s += cpart[(size_t)ch * 32768 + i];
  out[i] = s;
}

extern "C" void kernel_launch(void* const* d_in, const int* in_sizes, int n_in,
                              void* d_out, int out_size, void* d_ws, size_t ws_size,
                              hipStream_t stream) {
  const float* dh   = (const float*)d_in[0];   // (32,1,1024)
  const float* enc  = (const float*)d_in[1];   // (2048,32,1024)
  const float* Wenc = (const float*)d_in[2];   // (1024,1024)
  const float* Wdec = (const float*)d_in[3];   // (1024,1024)
  const float* Vatt = (const float*)d_in[4];   // (1,1024)
  float* out = (float*)d_out;                  // [0,32768) context, [32768,98304) alpha

  float* ws = (float*)d_ws;
  float* q      = ws;                                   // 32768
  float* qpart  = ws + 32768;                           // 262144
  float* lpart  = ws + 294912;                          // 262144
  float* cpart  = ws + 557056;                          // 32*32768 = 1048576
  unsigned short* Wbf   = (unsigned short*)(ws + 1605632);  // 1Mi bf16
  unsigned short* encbf = (unsigned short*)(ws + 2129920);  // 64Mi bf16

  conv_bf16_k<<<dim3(512),   dim3(256), 0, stream>>>(Wenc, Wbf);
  qpart_k    <<<dim3(32),    dim3(256), 0, stream>>>(dh, Wdec, qpart);
  qred_k     <<<dim3(128),   dim3(256), 0, stream>>>(qpart, q);
  conv_bf16_k<<<dim3(32768), dim3(256), 0, stream>>>(enc, encbf);
  gemm8p     <<<dim3(1024),  dim3(512), 0, stream>>>(encbf, Wbf, q, Vatt, lpart);
  softmax_k  <<<dim3(BATCH),     dim3(256), 0, stream>>>(lpart, out + 32768);
  ctx_part_k <<<dim3(BATCH*NCH), dim3(256), 0, stream>>>(encbf, out + 32768, cpart);
  ctxred_k   <<<dim3(128),       dim3(256), 0, stream>>>(cpart, out);
}

// Round 9
// 274.080 us; speedup vs baseline: 1.7111x; 1.0934x over previous
//
#include <hip/hip_runtime.h>
#include <hip/hip_bf16.h>
#include <math.h>

#define SEQ   2048
#define BATCH 32
#define DIM   1024
#define MROWS (SEQ*BATCH)   // 65536 rows, r = s*32 + b
#define NT2   4             // 1024 / 256 N-tiles
#define NCH   16            // context s-chunks (x2 sub-chunks inside kernel)
#define NKT   16            // K-tiles of 64

typedef __attribute__((ext_vector_type(8))) short short8;
typedef __attribute__((ext_vector_type(8))) unsigned short u16x8;
typedef __attribute__((ext_vector_type(4))) float f32x4;

__device__ __forceinline__ unsigned short f2bf(float f) {
  unsigned u = __builtin_bit_cast(unsigned, f);
  u += 0x7FFFu + ((u >> 16) & 1u);      // round-to-nearest-even
  return (unsigned short)(u >> 16);
}

// async global -> LDS, 16 B per lane (dest = wave-uniform base + lane*16)
__device__ __forceinline__ void gl16(const unsigned short* g, unsigned short* l) {
  __builtin_amdgcn_global_load_lds(
      (const __attribute__((address_space(1))) unsigned int*)g,
      (__attribute__((address_space(3))) unsigned int*)l, 16, 0, 0);
}

// ---------------- fp32 -> bf16 bulk convert ----------------
__global__ __launch_bounds__(256) void conv_bf16_k(const float* __restrict__ src,
                                                   unsigned short* __restrict__ dst) {
  size_t i = ((size_t)blockIdx.x * 256 + threadIdx.x) * 8;
  f32x4 a = __builtin_nontemporal_load(reinterpret_cast<const f32x4*>(src + i));
  f32x4 b = __builtin_nontemporal_load(reinterpret_cast<const f32x4*>(src + i + 4));
  u16x8 o;
  o[0] = f2bf(a[0]); o[1] = f2bf(a[1]); o[2] = f2bf(a[2]); o[3] = f2bf(a[3]);
  o[4] = f2bf(b[0]); o[5] = f2bf(b[1]); o[6] = f2bf(b[2]); o[7] = f2bf(b[3]);
  *reinterpret_cast<u16x8*>(dst + i) = o;
}

// ---------------- q[b,e] = sum_d dh[b,d] * W_dec[e,d] ----------------
__global__ __launch_bounds__(256) void qpart_k(const float* __restrict__ dh,
                                               const float* __restrict__ Wd,
                                               float* __restrict__ qpart) {
  const int bx = blockIdx.x;        // 32 blocks
  const int eb = bx & 3;            // 4 e-blocks of 256
  const int dc = bx >> 2;           // 8 d-chunks of 128
  __shared__ float ldh[BATCH][128];
  const int tid = threadIdx.x;
#pragma unroll
  for (int i = 0; i < 4; ++i) {
    int idx = tid + i * 256;
    int bb = idx >> 5, d4 = idx & 31;
    float4 v = *reinterpret_cast<const float4*>(&dh[(size_t)bb * DIM + dc * 128 + d4 * 4]);
    *reinterpret_cast<float4*>(&ldh[bb][d4 * 4]) = v;
  }
  __syncthreads();
  const int e = eb * 256 + tid;
  float acc[BATCH];
#pragma unroll
  for (int b = 0; b < BATCH; ++b) acc[b] = 0.f;
  for (int d4 = 0; d4 < 32; ++d4) {
    float4 w = *reinterpret_cast<const float4*>(&Wd[(size_t)e * DIM + dc * 128 + d4 * 4]);
#pragma unroll
    for (int b = 0; b < BATCH; ++b) {
      float4 h = *reinterpret_cast<const float4*>(&ldh[b][d4 * 4]);
      acc[b] += w.x * h.x + w.y * h.y + w.z * h.z + w.w * h.w;
    }
  }
#pragma unroll
  for (int b = 0; b < BATCH; ++b)
    qpart[((size_t)dc * BATCH + b) * DIM + e] = acc[b];
}

__global__ __launch_bounds__(256) void qred_k(const float* __restrict__ qpart,
                                              float* __restrict__ q) {
  int i = blockIdx.x * 256 + threadIdx.x;
  float s = 0.f;
#pragma unroll
  for (int dc = 0; dc < 8; ++dc) s += qpart[(size_t)dc * 32768 + i];
  q[i] = s;
}

// ============ 256^2 8-phase fused GEMM (R6 structure, compiler-counted lgkm) ========
// Identical to the 160us R6 kernel EXCEPT: the per-phase explicit
// "s_waitcnt lgkmcnt(0) + sched_barrier(0)" fence is removed. All ds_reads are
// plain-C loads consumed by same-phase MFMAs -> compiler emits precise counted
// lgkmcnt waits (m97 evidence); removing the pin lets early MFMAs overlap the
// tail ds_reads. gl16 staging ordering (vmcnt + barriers) unchanged.
#define BARR  __builtin_amdgcn_s_barrier()
#define VMC(n) asm volatile("s_waitcnt vmcnt(" #n ")" ::: "memory")

#define STAGE_A(t, h) do {                                                        \
    const unsigned short* gb_ = Abase + (size_t)(t) * 64;                         \
    char* lb_ = arena + (((t) & 1) * 65536) + (h) * 16384;                        \
    gl16(gb_ + (size_t)(gA0 + (h) * 64) * 1024 + cSt * 8,                         \
         (unsigned short*)lb_ + w * 512);                                         \
    gl16(gb_ + (size_t)(gA0 + 128 + (h) * 64) * 1024 + cSt * 8,                   \
         (unsigned short*)(lb_ + 8192) + w * 512);                                \
  } while (0)

#define STAGE_B(t, h) do {                                                        \
    const unsigned short* gb_ = Bbase + (size_t)(t) * 64;                         \
    char* lb_ = arena + (((t) & 1) * 65536) + 32768 + (h) * 16384;                \
    gl16(gb_ + (size_t)(gB0 + (h) * 32) * 1024 + cSt * 8,                         \
         (unsigned short*)lb_ + w * 512);                                         \
    gl16(gb_ + (size_t)(gB0 + 128 + (h) * 32) * 1024 + cSt * 8,                   \
         (unsigned short*)(lb_ + 8192) + w * 512);                                \
  } while (0)

#define LOAD_A(d, MH) do {                                                        \
    const char* bA_ = arena + (d) * 65536 + (MH) * 16384;                         \
    _Pragma("unroll") for (int i_ = 0; i_ < 4; ++i_)                              \
    _Pragma("unroll") for (int ks_ = 0; ks_ < 2; ++ks_) {                         \
      int lrow_ = wr * 64 + i_ * 16 + fr;                                         \
      int lc_ = (ks_ * 4 + kq) ^ (fr & 7);                                        \
      a[i_][ks_] = *(const short8*)(bA_ + lrow_ * 128 + lc_ * 16);                \
    } } while (0)

#define LOAD_B(d, NH) do {                                                        \
    const char* bB_ = arena + (d) * 65536 + 32768 + (NH) * 16384;                 \
    _Pragma("unroll") for (int j_ = 0; j_ < 2; ++j_)                              \
    _Pragma("unroll") for (int ks_ = 0; ks_ < 2; ++ks_) {                         \
      int lrow_ = wc * 32 + j_ * 16 + fr;                                         \
      int lc_ = (ks_ * 4 + kq) ^ (fr & 7);                                        \
      b[NH][j_][ks_] = *(const short8*)(bB_ + lrow_ * 128 + lc_ * 16);            \
    } } while (0)

#define DO_QUAD(MH, NH) do {                                                      \
    __builtin_amdgcn_s_setprio(1);                                                \
    _Pragma("unroll") for (int i_ = 0; i_ < 4; ++i_)                              \
    _Pragma("unroll") for (int j_ = 0; j_ < 2; ++j_)                              \
    _Pragma("unroll") for (int ks_ = 0; ks_ < 2; ++ks_)                           \
      acc[(MH) * 4 + i_][(NH) * 2 + j_] =                                         \
          __builtin_amdgcn_mfma_f32_16x16x32_bf16(                                \
              a[i_][ks_], b[NH][j_][ks_], acc[(MH) * 4 + i_][(NH) * 2 + j_],      \
              0, 0, 0);                                                           \
    __builtin_amdgcn_s_setprio(0);                                                \
  } while (0)

__global__ __launch_bounds__(512, 2) void gemm8p(const unsigned short* __restrict__ A,
                                                 const unsigned short* __restrict__ B,
                                                 const float* __restrict__ q,
                                                 const float* __restrict__ V,
                                                 float* __restrict__ lpart) {
  __shared__ __align__(16) char arena[131072];   // 2 bufs x (A 32KB | B 32KB)

  const int bid = blockIdx.x;
  const int wg = (bid & 7) * 128 + (bid >> 3);   // XCD-bijective (1024 % 8 == 0)
  const int mt = wg >> 2, nt = wg & 3;
  const int row0 = mt * 256, col0 = nt * 256;
  const int tid = threadIdx.x;
  const int lane = tid & 63, w = tid >> 6;
  const int wr = w >> 2, wc = w & 3;             // 2 x 4 waves, each 128x64 out
  const int fr = lane & 15, kq = lane >> 4;

  // stage lane geometry: slot u -> piece lrow = u>>3, chunk (u&7)^(lrow&7)
  const int lr0 = tid >> 3;                      // 0..63
  const int cSt = (tid & 7) ^ (lr0 & 7);
  const int gA0 = lr0;                           // A piece h: rows gA0+h*64, +128
  const int gB0 = (lr0 & 31) + (lr0 >> 5) * 64;  // B piece h: rows gB0+h*32, +128

  const unsigned short* Abase = A + (size_t)row0 * DIM;
  const unsigned short* Bbase = B + (size_t)col0 * DIM;

  f32x4 acc[8][4];
#pragma unroll
  for (int i = 0; i < 8; ++i)
#pragma unroll
    for (int j = 0; j < 4; ++j) acc[i][j] = (f32x4)(0.f);

  short8 a[4][2];        // current A-half fragments (reloaded at p3/p7)
  short8 b[2][2][2];     // both B halves: NH x j x ks

  // ---- prologue: tile0 full + tile1 h0 pieces; drain; barrier ----
  STAGE_A(0, 0); STAGE_B(0, 0); STAGE_A(0, 1); STAGE_B(0, 1);
  STAGE_A(1, 0); STAGE_B(1, 0);
  VMC(0);
  BARR;

#pragma unroll 1
  for (int t2 = 0; t2 < NKT; t2 += 2) {
    const bool last = (t2 == NKT - 2);
    // p1: tile t2 (buf0), quad (M0,N0)
    LOAD_A(0, 0); LOAD_B(0, 0);
    STAGE_A(t2 + 1, 1);
    BARR; DO_QUAD(0, 0); BARR;
    // p2: (M0,N1)
    LOAD_B(0, 1);
    STAGE_B(t2 + 1, 1);
    BARR; DO_QUAD(0, 1); BARR;
    // p3: (M1,N0)
    LOAD_A(0, 1);
    if (!last) STAGE_A(t2 + 2, 0);
    BARR; DO_QUAD(1, 0); BARR;
    // p4: (M1,N1) + K-tile drain point
    if (!last) { STAGE_B(t2 + 2, 0); VMC(4); } else { VMC(0); }
    BARR; DO_QUAD(1, 1); BARR;
    // p5: tile t2+1 (buf1), quad (M0,N0)
    LOAD_A(1, 0); LOAD_B(1, 0);
    if (!last) STAGE_A(t2 + 2, 1);
    BARR; DO_QUAD(0, 0); BARR;
    // p6: (M0,N1)
    LOAD_B(1, 1);
    if (!last) STAGE_B(t2 + 2, 1);
    BARR; DO_QUAD(0, 1); BARR;
    // p7: (M1,N0)
    LOAD_A(1, 1);
    if (!last) STAGE_A(t2 + 3, 0);
    BARR; DO_QUAD(1, 0); BARR;
    // p8: (M1,N1) + K-tile drain point
    if (!last) { STAGE_B(t2 + 3, 0); VMC(4); }
    BARR; DO_QUAD(1, 1); BARR;
  }

  // ================= epilogue =================
  __syncthreads();                 // staging LDS dead; overlay q/V/red
  float* qld = (float*)arena;                    // [32][260] padded
  float* vld = (float*)(arena + 33280);          // [256]
  float* red = (float*)(arena + 34304);          // [4][256]
#pragma unroll
  for (int i = 0; i < 4; ++i) {
    int id = i * 512 + tid;                      // 2048 float4s
    int bb = id >> 6, e4 = id & 63;
    float4 v = *(const float4*)&q[(size_t)bb * DIM + col0 + e4 * 4];
    *(float4*)&qld[bb * 260 + e4 * 4] = v;
  }
  if (tid < 64) *(float4*)&vld[tid * 4] = *(const float4*)&V[col0 + tid * 4];
  __syncthreads();

#pragma unroll
  for (int mf = 0; mf < 8; ++mf) {
#pragma unroll
    for (int reg = 0; reg < 4; ++reg) {
      const int m_loc = wr * 128 + mf * 16 + kq * 4 + reg;
      const int bb = m_loc & 31;                 // row0 % 32 == 0
      float val = 0.f;
#pragma unroll
      for (int nf = 0; nf < 4; ++nf) {
        const int el = wc * 64 + nf * 16 + fr;
        float x = acc[mf][nf][reg] + qld[bb * 260 + el];
        float g = __expf(2.f * x);
        float tnh = 1.f - 2.f * __builtin_amdgcn_rcpf(g + 1.f);
        val += tnh * vld[el];
      }
      val += __shfl_xor(val, 1); val += __shfl_xor(val, 2);
      val += __shfl_xor(val, 4); val += __shfl_xor(val, 8);
      if (fr == 0) red[wc * 256 + m_loc] = val;
    }
  }
  __syncthreads();
  if (tid < 256) {
    float s = red[tid] + red[256 + tid] + red[512 + tid] + red[768 + tid];
    lpart[(size_t)(row0 + tid) * NT2 + nt] = s;
  }
}

// ---------------- softmax over seq per batch ----------------
__global__ __launch_bounds__(256) void softmax_k(const float* __restrict__ lpart,
                                                 float* __restrict__ alpha) {
  const int b = blockIdx.x;
  __shared__ float lv[SEQ];
  __shared__ float sred[4];
  const int tid = threadIdx.x;
  float mx = -1e30f;
  for (int s = tid; s < SEQ; s += 256) {
    const float* p = &lpart[(size_t)(s * BATCH + b) * NT2];
    float v = p[0] + p[1] + p[2] + p[3];
    lv[s] = v;
    mx = fmaxf(mx, v);
  }
#pragma unroll
  for (int off = 32; off >= 1; off >>= 1) mx = fmaxf(mx, __shfl_xor(mx, off));
  if ((tid & 63) == 0) sred[tid >> 6] = mx;
  __syncthreads();
  mx = fmaxf(fmaxf(sred[0], sred[1]), fmaxf(sred[2], sred[3]));
  __syncthreads();
  float sm = 0.f;
  for (int s = tid; s < SEQ; s += 256) {
    float e = expf(lv[s] - mx);
    lv[s] = e;
    sm += e;
  }
#pragma unroll
  for (int off = 32; off >= 1; off >>= 1) sm += __shfl_xor(sm, off);
  if ((tid & 63) == 0) sred[tid >> 6] = sm;
  __syncthreads();
  const float inv = 1.f / (sred[0] + sred[1] + sred[2] + sred[3]);
  for (int s = tid; s < SEQ; s += 256)
    alpha[(size_t)b * SEQ + s] = lv[s] * inv;
}

// ---------------- context partials from bf16 enc copy ----------------
__global__ __launch_bounds__(256) void ctx_part_k(const unsigned short* __restrict__ encbf,
                                                  const float* __restrict__ alpha,
                                                  float* __restrict__ cpart) {
  const int blk = blockIdx.x;                   // 512 blocks
  const int b = blk & 31;
  const int ch = blk >> 5;                      // 0..15
  const int tid = threadIdx.x;
  const int g = tid >> 7;                       // 0/1 sub-chunk
  const int d0 = (tid & 127) * 8;
  const int s0 = ch * (SEQ / NCH);
  float acc8[8];
#pragma unroll
  for (int k = 0; k < 8; ++k) acc8[k] = 0.f;
#pragma unroll 4
  for (int i = 0; i < SEQ / NCH; i += 2) {
    const int s = s0 + i + g;
    const float a = alpha[(size_t)b * SEQ + s];
    u16x8 v = *reinterpret_cast<const u16x8*>(&encbf[((size_t)s * BATCH + b) * DIM + d0]);
#pragma unroll
    for (int k = 0; k < 8; ++k) {
      float f = __builtin_bit_cast(float, (unsigned)v[k] << 16);
      acc8[k] += a * f;
    }
  }
  size_t o = ((size_t)(ch * 2 + g) * BATCH + b) * DIM + d0;
  float4 lo = {acc8[0], acc8[1], acc8[2], acc8[3]};
  float4 hi = {acc8[4], acc8[5], acc8[6], acc8[7]};
  *(float4*)&cpart[o] = lo;
  *(float4*)&cpart[o + 4] = hi;
}

__global__ __launch_bounds__(256) void ctxred_k(const float* __restrict__ cpart,
                                                float* __restrict__ out) {
  int i = blockIdx.x * 256 + threadIdx.x;
  float s = 0.f;
#pragma unroll
  for (int ch = 0; ch < 32; ++ch) s += cpart[(size_t)ch * 32768 + i];
  out[i] = s;
}

extern "C" void kernel_launch(void* const* d_in, const int* in_sizes, int n_in,
                              void* d_out, int out_size, void* d_ws, size_t ws_size,
                              hipStream_t stream) {
  const float* dh   = (const float*)d_in[0];   // (32,1,1024)
  const float* enc  = (const float*)d_in[1];   // (2048,32,1024)
  const float* Wenc = (const float*)d_in[2];   // (1024,1024)
  const float* Wdec = (const float*)d_in[3];   // (1024,1024)
  const float* Vatt = (const float*)d_in[4];   // (1,1024)
  float* out = (float*)d_out;                  // [0,32768) context, [32768,98304) alpha

  float* ws = (float*)d_ws;
  float* q      = ws;                                   // 32768
  float* qpart  = ws + 32768;                           // 262144
  float* lpart  = ws + 294912;                          // 262144
  float* cpart  = ws + 557056;                          // 32*32768 = 1048576
  unsigned short* Wbf   = (unsigned short*)(ws + 1605632);  // 1Mi bf16
  unsigned short* encbf = (unsigned short*)(ws + 2129920);  // 64Mi bf16

  conv_bf16_k<<<dim3(512),   dim3(256), 0, stream>>>(Wenc, Wbf);
  qpart_k    <<<dim3(32),    dim3(256), 0, stream>>>(dh, Wdec, qpart);
  qred_k     <<<dim3(128),   dim3(256), 0, stream>>>(qpart, q);
  conv_bf16_k<<<dim3(32768), dim3(256), 0, stream>>>(enc, encbf);
  gemm8p     <<<dim3(1024),  dim3(512), 0, stream>>>(encbf, Wbf, q, Vatt, lpart);
  softmax_k  <<<dim3(BATCH),     dim3(256), 0, stream>>>(lpart, out + 32768);
  ctx_part_k <<<dim3(BATCH*NCH), dim3(256), 0, stream>>>(encbf, out + 32768, cpart);
  ctxred_k   <<<dim3(128),       dim3(256), 0, stream>>>(cpart, out);
}